// Round 1
// baseline (790.857 us; speedup 1.0000x reference)
//
#include <hip/hip_runtime.h>
#include <hip/hip_bf16.h>

// Problem constants
#define TT   1024
#define FF   256
#define DK   64

typedef float  f4v  __attribute__((ext_vector_type(4)));
typedef float  f16v __attribute__((ext_vector_type(16)));
typedef __bf16 bf8v __attribute__((ext_vector_type(8)));
typedef unsigned short us8v __attribute__((ext_vector_type(8)));
typedef unsigned short us4v __attribute__((ext_vector_type(4)));

static __device__ __forceinline__ unsigned short f2bf(float x) {
    return __builtin_bit_cast(unsigned short, (__bf16)x);
}
static __device__ __forceinline__ float bf2f(unsigned short u) {
    return (float)__builtin_bit_cast(__bf16, u);
}
static __device__ __forceinline__ bf8v us2bf(us8v v) {
    return __builtin_bit_cast(bf8v, v);
}

// ---------------------------------------------------------------------------
// K1: LayerNorm(x) + Q/K/V projections (fp32 VALU), output bf16 per-head
// layout [bh][t][64], bh = b*4+h.  512 blocks x 256 thr, 16 rows/block.
// ---------------------------------------------------------------------------
__global__ __launch_bounds__(256) void k_qkv(
    const float* __restrict__ x, const float* __restrict__ qin,
    const float* __restrict__ lng, const float* __restrict__ lnb,
    const float* __restrict__ Wq, const float* __restrict__ bq,
    const float* __restrict__ Wk, const float* __restrict__ bk,
    const float* __restrict__ Wv, const float* __restrict__ bv,
    unsigned short* __restrict__ Qh, unsigned short* __restrict__ Kh,
    unsigned short* __restrict__ Vh)
{
    __shared__ float xn[16][FF];
    __shared__ float qi[16][FF];
    const int tid  = threadIdx.x;
    const int lane = tid & 63;
    const int wv   = tid >> 6;
    const int r0   = blockIdx.x << 4;

    #pragma unroll
    for (int rr = 0; rr < 4; ++rr) {
        const int r   = (wv << 2) + rr;
        const int row = r0 + r;
        float v[4], qv[4];
        float s = 0.f, s2 = 0.f;
        #pragma unroll
        for (int c4 = 0; c4 < 4; ++c4) {
            v[c4]  = x[row * FF + (c4 << 6) + lane];
            qv[c4] = qin[row * FF + (c4 << 6) + lane];
            s  += v[c4];
            s2 += v[c4] * v[c4];
        }
        #pragma unroll
        for (int off = 1; off < 64; off <<= 1) {
            s  += __shfl_xor(s, off);
            s2 += __shfl_xor(s2, off);
        }
        const float mu  = s * (1.f / FF);
        const float rsd = rsqrtf(s2 * (1.f / FF) - mu * mu + 1e-5f);
        #pragma unroll
        for (int c4 = 0; c4 < 4; ++c4) {
            const int c = (c4 << 6) + lane;
            xn[r][c] = (v[c4] - mu) * rsd * lng[c] + lnb[c];
            qi[r][c] = qv[c4];
        }
    }
    __syncthreads();

    const int cg = tid & 31;   // cols cg + 32k
    const int rg = tid >> 5;   // rows rg*2, rg*2+1
    const int bb = r0 >> 10;   // batch (16 rows never straddle b since T%16==0)

    for (int mm = 0; mm < 3; ++mm) {
        const float* A  = (mm == 0) ? &qi[0][0] : &xn[0][0];
        const float* W  = (mm == 0) ? Wq : (mm == 1) ? Wk : Wv;
        const float* bs = (mm == 0) ? bq : (mm == 1) ? bk : bv;
        unsigned short* dst = (mm == 0) ? Qh : (mm == 1) ? Kh : Vh;

        float acc[2][8];
        #pragma unroll
        for (int r = 0; r < 2; ++r)
            #pragma unroll
            for (int k = 0; k < 8; ++k) acc[r][k] = 0.f;

        for (int i = 0; i < FF; i += 4) {
            const f4v a0 = *(const f4v*)(A + (rg*2+0)*FF + i);
            const f4v a1 = *(const f4v*)(A + (rg*2+1)*FF + i);
            #pragma unroll
            for (int k = 0; k < 8; ++k) {
                const int c = cg + (k << 5);
                const float w0 = W[(i+0)*FF + c];
                const float w1 = W[(i+1)*FF + c];
                const float w2 = W[(i+2)*FF + c];
                const float w3 = W[(i+3)*FF + c];
                acc[0][k] += a0[0]*w0 + a0[1]*w1 + a0[2]*w2 + a0[3]*w3;
                acc[1][k] += a1[0]*w0 + a1[1]*w1 + a1[2]*w2 + a1[3]*w3;
            }
        }
        #pragma unroll
        for (int r = 0; r < 2; ++r) {
            const int t = (r0 + rg*2 + r) & (TT - 1);
            #pragma unroll
            for (int k = 0; k < 8; ++k) {
                const int c = cg + (k << 5);
                const int h = c >> 6, d = c & 63;
                dst[(((bb << 2) + h) << 16) + (t << 6) + d] = f2bf(acc[r][k] + bs[c]);
            }
        }
    }
}

// ---------------------------------------------------------------------------
// K2: relative-position term.  Per fixed query q:  Bmat[bh, t] = Q_q[32x64] @
// P_q[t,64]^T  -- a real GEMM over the 32 (b,h) rows, so each pos_k element is
// read from HBM exactly ONCE.  MFMA 32x32x16 bf16, fragments loaded straight
// from global (A rows = Qh rows, B rows = pos_k rows; both 8-contiguous).
// Grid (2, 512): x = t-chunk of 512 (wave covers 128 t), y = q within half.
// ---------------------------------------------------------------------------
__global__ __launch_bounds__(256) void k_bterm(
    const unsigned short* __restrict__ Qh, const float* __restrict__ posk,
    unsigned short* __restrict__ Bm, int qbase)
{
    const int tid  = threadIdx.x;
    const int lane = tid & 63;
    const int wv   = tid >> 6;
    const int gq   = lane >> 5;   // half-wave group
    const int m    = lane & 31;   // A row (bh) / B col (t offset)
    const int ql   = blockIdx.y;  // 0..511 local q in half
    const int q    = qbase + ql;

    // A fragments: A[m=bh][k=d], k = gq*8+j (+16 per kk). Loaded once, reused.
    bf8v afr[4];
    #pragma unroll
    for (int kk = 0; kk < 4; ++kk) {
        const int d0 = (kk << 4) + (gq << 3);
        afr[kk] = us2bf(*(const us8v*)&Qh[(m << 16) + (q << 6) + d0]);
    }

    const int t0w = (blockIdx.x << 9) + (wv << 7);
    for (int st = 0; st < 4; ++st) {
        const int t = t0w + (st << 5) + m;
        bf8v bfr[4];
        #pragma unroll
        for (int kk = 0; kk < 4; ++kk) {
            const int d0 = (kk << 4) + (gq << 3);
            const f4v p0 = *(const f4v*)&posk[(((q << 10) + t) << 6) + d0];
            const f4v p1 = *(const f4v*)&posk[(((q << 10) + t) << 6) + d0 + 4];
            bf8v bbv;
            bbv[0] = (__bf16)p0[0]; bbv[1] = (__bf16)p0[1];
            bbv[2] = (__bf16)p0[2]; bbv[3] = (__bf16)p0[3];
            bbv[4] = (__bf16)p1[0]; bbv[5] = (__bf16)p1[1];
            bbv[6] = (__bf16)p1[2]; bbv[7] = (__bf16)p1[3];
            bfr[kk] = bbv;
        }
        f16v acc;
        #pragma unroll
        for (int i = 0; i < 16; ++i) acc[i] = 0.f;
        #pragma unroll
        for (int kk = 0; kk < 4; ++kk)
            acc = __builtin_amdgcn_mfma_f32_32x32x16_bf16(afr[kk], bfr[kk], acc, 0, 0, 0);
        // D layout (verified m74/m101): col=lane&31, row=(reg&3)+8*(reg>>2)+4*(lane>>5)
        #pragma unroll
        for (int reg = 0; reg < 16; ++reg) {
            const int bhr = (reg & 3) + ((reg >> 2) << 3) + (gq << 2);
            Bm[(bhr << 19) + (ql << 10) + t] = f2bf(acc[reg]);
        }
    }
}

// ---------------------------------------------------------------------------
// K3: flash attention per (b,h, 32-query tile).  S = Q K^T (MFMA 16x16x32),
// + Bmat + mask, online softmax, P round-trips LDS (m120 pattern), PV MFMA.
// 4 waves; wave w owns t' range w*32 (S) and d range w*16 (O).  BT=128, 8 it.
// ---------------------------------------------------------------------------
__global__ __launch_bounds__(256) void k_attn(
    const unsigned short* __restrict__ Qh, const unsigned short* __restrict__ Kh,
    const unsigned short* __restrict__ Vh, const unsigned short* __restrict__ Bm,
    const int* __restrict__ mask, float* __restrict__ aout, int qbase)
{
    __shared__ __align__(16) unsigned short Qs[32 * 72];
    __shared__ __align__(16) unsigned short Ks[128 * 72];
    __shared__ __align__(16) unsigned short Vs[128 * 76];
    __shared__ __align__(16) unsigned short Ps[32 * 136];
    __shared__ float m_s[32], l_s[32];
    __shared__ float wmax[4][32], wsum[4][32];

    const int tid  = threadIdx.x;
    const int lane = tid & 63;
    const int wv   = tid >> 6;
    const int l15  = lane & 15;
    const int quad = lane >> 4;
    const int bh   = blockIdx.x & 31;
    const int qt   = blockIdx.x >> 5;
    const int b    = bh >> 2;
    const int h    = bh & 3;
    const int q0l  = qt << 5;          // local (within half)
    const int q0g  = qbase + q0l;      // global query row base

    if (tid < 32) { m_s[tid] = -3.0e38f; l_s[tid] = 0.f; }
    {   // Q tile, once
        const int idx = tid << 3;
        const int r = idx >> 6, d0 = idx & 63;
        *(us8v*)&Qs[r * 72 + d0] =
            *(const us8v*)&Qh[(bh << 16) + ((q0g + r) << 6) + d0];
    }

    f4v o0, o1;
    #pragma unroll
    for (int i = 0; i < 4; ++i) { o0[i] = 0.f; o1[i] = 0.f; }

    for (int it = 0; it < 8; ++it) {
        const int t0 = it << 7;
        #pragma unroll
        for (int u = 0; u < 4; ++u) {           // K tile: 1024 us8 chunks
            const int ch = tid + (u << 8);
            const int tr = ch >> 3, c = ch & 7;
            *(us8v*)&Ks[tr * 72 + (c << 3)] =
                *(const us8v*)&Kh[(bh << 16) + ((t0 + tr) << 6) + (c << 3)];
        }
        #pragma unroll
        for (int u = 0; u < 8; ++u) {           // V tile: us4 chunks (stride 76)
            const int ch = tid + (u << 8);
            const int tr = ch >> 4, c4 = ch & 15;
            *(us4v*)&Vs[tr * 76 + (c4 << 2)] =
                *(const us4v*)&Vh[(bh << 16) + ((t0 + tr) << 6) + (c4 << 2)];
        }
        __syncthreads();

        // S = Q K^T : A[m=q][k=d], B[k=d][n=t'], k = quad*8+j (+32 per kk)
        f4v s00, s01, s10, s11;
        #pragma unroll
        for (int i = 0; i < 4; ++i) { s00[i]=0.f; s01[i]=0.f; s10[i]=0.f; s11[i]=0.f; }
        #pragma unroll
        for (int kk = 0; kk < 2; ++kk) {
            const int d0 = (kk << 5) + (quad << 3);
            const bf8v aq0 = us2bf(*(const us8v*)&Qs[l15 * 72 + d0]);
            const bf8v aq1 = us2bf(*(const us8v*)&Qs[(16 + l15) * 72 + d0]);
            const bf8v kb0 = us2bf(*(const us8v*)&Ks[((wv << 5) + l15) * 72 + d0]);
            const bf8v kb1 = us2bf(*(const us8v*)&Ks[((wv << 5) + 16 + l15) * 72 + d0]);
            s00 = __builtin_amdgcn_mfma_f32_16x16x32_bf16(aq0, kb0, s00, 0, 0, 0);
            s01 = __builtin_amdgcn_mfma_f32_16x16x32_bf16(aq0, kb1, s01, 0, 0, 0);
            s10 = __builtin_amdgcn_mfma_f32_16x16x32_bf16(aq1, kb0, s10, 0, 0, 0);
            s11 = __builtin_amdgcn_mfma_f32_16x16x32_bf16(aq1, kb1, s11, 0, 0, 0);
        }

        // scores: C/D layout col=lane&15 (t'), row=quad*4+reg (q)
        float sv[2][2][4];
        #pragma unroll
        for (int mf = 0; mf < 2; ++mf)
            #pragma unroll
            for (int nf = 0; nf < 2; ++nf) {
                const f4v sfr = (mf == 0) ? (nf == 0 ? s00 : s01)
                                          : (nf == 0 ? s10 : s11);
                const int tl = (wv << 5) + (nf << 4) + l15;
                const int t  = t0 + tl;
                #pragma unroll
                for (int r = 0; r < 4; ++r) {
                    const int q = (mf << 4) + (quad << 2) + r;
                    const float val =
                        (sfr[r] + bf2f(Bm[(bh << 19) + ((q0l + q) << 10) + t])) * 0.125f;
                    const int mk = mask[(((b << 10) + q0g + q) << 10) + t];
                    sv[mf][nf][r] = mk ? val : -3.0e38f;
                }
            }

        // per-wave row maxes (row q lives on the 16 lanes of one quad group)
        float rmax[2][4];
        #pragma unroll
        for (int mf = 0; mf < 2; ++mf)
            #pragma unroll
            for (int r = 0; r < 4; ++r) {
                float vx = fmaxf(sv[mf][0][r], sv[mf][1][r]);
                vx = fmaxf(vx, __shfl_xor(vx, 1));
                vx = fmaxf(vx, __shfl_xor(vx, 2));
                vx = fmaxf(vx, __shfl_xor(vx, 4));
                vx = fmaxf(vx, __shfl_xor(vx, 8));
                rmax[mf][r] = vx;
            }
        if (l15 == 0) {
            #pragma unroll
            for (int mf = 0; mf < 2; ++mf)
                #pragma unroll
                for (int r = 0; r < 4; ++r)
                    wmax[wv][(mf << 4) + (quad << 2) + r] = rmax[mf][r];
        }
        __syncthreads();

        float alpha[2][4], mnew[2][4];
        #pragma unroll
        for (int mf = 0; mf < 2; ++mf)
            #pragma unroll
            for (int r = 0; r < 4; ++r) {
                const int q = (mf << 4) + (quad << 2) + r;
                const float tm = fmaxf(fmaxf(wmax[0][q], wmax[1][q]),
                                       fmaxf(wmax[2][q], wmax[3][q]));
                const float mo = m_s[q];
                const float mn = fmaxf(mo, tm);
                mnew[mf][r]  = mn;
                alpha[mf][r] = __expf(mo - mn);
            }
        #pragma unroll
        for (int mf = 0; mf < 2; ++mf)
            #pragma unroll
            for (int r = 0; r < 4; ++r) {
                const int q = (mf << 4) + (quad << 2) + r;
                const float p0 = __expf(sv[mf][0][r] - mnew[mf][r]);
                const float p1 = __expf(sv[mf][1][r] - mnew[mf][r]);
                Ps[q * 136 + (wv << 5) + l15]      = f2bf(p0);
                Ps[q * 136 + (wv << 5) + 16 + l15] = f2bf(p1);
                float rs2 = p0 + p1;
                rs2 += __shfl_xor(rs2, 1);
                rs2 += __shfl_xor(rs2, 2);
                rs2 += __shfl_xor(rs2, 4);
                rs2 += __shfl_xor(rs2, 8);
                if (l15 == 0) wsum[wv][q] = rs2;
            }
        #pragma unroll
        for (int r = 0; r < 4; ++r) { o0[r] *= alpha[0][r]; o1[r] *= alpha[1][r]; }
        __syncthreads();

        if (tid < 32) {   // commit running stats (reads pre-barrier wmax/wsum)
            const int q = tid;
            const float tm = fmaxf(fmaxf(wmax[0][q], wmax[1][q]),
                                   fmaxf(wmax[2][q], wmax[3][q]));
            const float mo = m_s[q];
            const float mn = fmaxf(mo, tm);
            l_s[q] = l_s[q] * __expf(mo - mn)
                   + (wsum[0][q] + wsum[1][q]) + (wsum[2][q] + wsum[3][q]);
            m_s[q] = mn;
        }

        // PV: A from Ps rows (b128), B from Vs via u16 gather; n = d = wv*16+l15
        #pragma unroll
        for (int kk = 0; kk < 4; ++kk) {
            us8v vb;
            #pragma unroll
            for (int j = 0; j < 8; ++j) {
                const int tl = (kk << 5) + (quad << 3) + j;
                vb[j] = Vs[tl * 76 + (wv << 4) + l15];
            }
            const bf8v vbf = us2bf(vb);
            const bf8v ap0 = us2bf(*(const us8v*)&Ps[l15 * 136 + (kk << 5) + (quad << 3)]);
            const bf8v ap1 = us2bf(*(const us8v*)&Ps[(16 + l15) * 136 + (kk << 5) + (quad << 3)]);
            o0 = __builtin_amdgcn_mfma_f32_16x16x32_bf16(ap0, vbf, o0, 0, 0, 0);
            o1 = __builtin_amdgcn_mfma_f32_16x16x32_bf16(ap1, vbf, o1, 0, 0, 0);
        }
        __syncthreads();   // protect Ks/Vs/Ps before next iteration's staging
    }

    const int d = (wv << 4) + l15;
    #pragma unroll
    for (int mf = 0; mf < 2; ++mf)
        #pragma unroll
        for (int r = 0; r < 4; ++r) {
            const int q = (mf << 4) + (quad << 2) + r;
            const float ov = (mf == 0) ? o0[r] : o1[r];
            aout[(((b << 10) + q0g + q) << 8) + (h << 6) + d] = ov / l_s[q];
        }
}

// ---------------------------------------------------------------------------
// K4: out = attn_out @ Wo + bo   (fp32 VALU, same shape as K1's GEMM)
// ---------------------------------------------------------------------------
__global__ __launch_bounds__(256) void k_oproj(
    const float* __restrict__ ain, const float* __restrict__ Wo,
    const float* __restrict__ bo, float* __restrict__ out)
{
    __shared__ float As[16][FF];
    const int tid = threadIdx.x;
    const int r0  = blockIdx.x << 4;
    #pragma unroll
    for (int u = 0; u < 4; ++u) {
        const int idx = (tid + (u << 8)) << 2;
        const int r = idx >> 8, c = idx & 255;
        *(f4v*)&As[r][c] = *(const f4v*)&ain[(r0 + r) * FF + c];
    }
    __syncthreads();
    const int cg = tid & 31;
    const int rg = tid >> 5;
    float acc[2][8];
    #pragma unroll
    for (int r = 0; r < 2; ++r)
        #pragma unroll
        for (int k = 0; k < 8; ++k) acc[r][k] = 0.f;
    for (int i = 0; i < FF; i += 4) {
        const f4v a0 = *(const f4v*)&As[rg*2+0][i];
        const f4v a1 = *(const f4v*)&As[rg*2+1][i];
        #pragma unroll
        for (int k = 0; k < 8; ++k) {
            const int c = cg + (k << 5);
            const float w0 = Wo[(i+0)*FF + c];
            const float w1 = Wo[(i+1)*FF + c];
            const float w2 = Wo[(i+2)*FF + c];
            const float w3 = Wo[(i+3)*FF + c];
            acc[0][k] += a0[0]*w0 + a0[1]*w1 + a0[2]*w2 + a0[3]*w3;
            acc[1][k] += a1[0]*w0 + a1[1]*w1 + a1[2]*w2 + a1[3]*w3;
        }
    }
    #pragma unroll
    for (int r = 0; r < 2; ++r) {
        const int row = r0 + rg*2 + r;
        #pragma unroll
        for (int k = 0; k < 8; ++k) {
            const int c = cg + (k << 5);
            out[row * FF + c] = acc[r][k] + bo[c];
        }
    }
}

// ---------------------------------------------------------------------------
// ws layout (bytes):  Qh 0..4M | Kh 4M..8M | Vh 8M..12M | aout 12M..20M |
// Bmat(half, 32x512x1024 bf16 = 32M) 20M..52M.   Total 52 MB.
// Query dim processed in 2 halves so the Bmat scratch stays at 32 MB.
// ---------------------------------------------------------------------------
extern "C" void kernel_launch(void* const* d_in, const int* in_sizes, int n_in,
                              void* d_out, int out_size, void* d_ws, size_t ws_size,
                              hipStream_t stream)
{
    const float* x    = (const float*)d_in[0];
    const float* qin  = (const float*)d_in[1];
    const float* posk = (const float*)d_in[2];
    const int*   mask = (const int*)d_in[3];
    const float* ln_g = (const float*)d_in[4];
    const float* ln_b = (const float*)d_in[5];
    const float* Wq   = (const float*)d_in[6];
    const float* bq   = (const float*)d_in[7];
    const float* Wk   = (const float*)d_in[8];
    const float* bk   = (const float*)d_in[9];
    const float* Wv   = (const float*)d_in[10];
    const float* bv   = (const float*)d_in[11];
    const float* Wo   = (const float*)d_in[12];
    const float* bo   = (const float*)d_in[13];
    float* out = (float*)d_out;

    char* ws = (char*)d_ws;
    unsigned short* Qh  = (unsigned short*)(ws);
    unsigned short* Kh  = (unsigned short*)(ws + (size_t)(4u << 20));
    unsigned short* Vh  = (unsigned short*)(ws + (size_t)(8u << 20));
    float*          aot = (float*)(ws + (size_t)(12u << 20));
    unsigned short* Bmw = (unsigned short*)(ws + (size_t)(20u << 20));

    hipLaunchKernelGGL(k_qkv, dim3(512), dim3(256), 0, stream,
                       x, qin, ln_g, ln_b, Wq, bq, Wk, bk, Wv, bv, Qh, Kh, Vh);
    for (int half = 0; half < 2; ++half) {
        const int qbase = half * 512;
        hipLaunchKernelGGL(k_bterm, dim3(2, 512), dim3(256), 0, stream,
                           Qh, posk, Bmw, qbase);
        hipLaunchKernelGGL(k_attn, dim3(512), dim3(256), 0, stream,
                           Qh, Kh, Vh, Bmw, mask, aot, qbase);
    }
    hipLaunchKernelGGL(k_oproj, dim3(512), dim3(256), 0, stream, aot, Wo, bo, out);
}

// Round 2
// 536.319 us; speedup vs baseline: 1.4746x; 1.4746x over previous
//
#include <hip/hip_runtime.h>
#include <hip/hip_bf16.h>

#define TT 1024
#define FF 256

typedef float  f4v  __attribute__((ext_vector_type(4)));
typedef float  f16v __attribute__((ext_vector_type(16)));
typedef __bf16 bf8v __attribute__((ext_vector_type(8)));
typedef unsigned short us8v __attribute__((ext_vector_type(8)));
typedef unsigned short us4v __attribute__((ext_vector_type(4)));

static __device__ __forceinline__ unsigned short f2bf(float x) {
    return __builtin_bit_cast(unsigned short, (__bf16)x);
}
static __device__ __forceinline__ float bf2f(unsigned short u) {
    return (float)__builtin_bit_cast(__bf16, u);
}
static __device__ __forceinline__ bf8v us2bf(us8v v) {
    return __builtin_bit_cast(bf8v, v);
}

// ---------------------------------------------------------------------------
// K0: weight prep — W[k][n] fp32 -> Wt[n][k] bf16, 4 matrices (Q,K,V,O).
// ---------------------------------------------------------------------------
__global__ __launch_bounds__(256) void k_wprep(
    const float* __restrict__ Wq, const float* __restrict__ Wk,
    const float* __restrict__ Wv, const float* __restrict__ Wo,
    unsigned short* __restrict__ Wt)
{
    __shared__ unsigned short T[32][36];
    const float* W = (blockIdx.y == 0) ? Wq : (blockIdx.y == 1) ? Wk
                   : (blockIdx.y == 2) ? Wv : Wo;
    unsigned short* dst = Wt + (blockIdx.y << 16);
    const int kt = (blockIdx.x >> 3) << 5, nt = (blockIdx.x & 7) << 5;
    const int r = threadIdx.x >> 3, c0 = (threadIdx.x & 7) << 2;
    const f4v w = *(const f4v*)&W[(kt + r) * FF + nt + c0];
    #pragma unroll
    for (int j = 0; j < 4; ++j) T[c0 + j][r] = f2bf(w[j]);
    __syncthreads();
    *(us4v*)&dst[(nt + r) * FF + kt + c0] = *(const us4v*)&T[r][c0];
}

// ---------------------------------------------------------------------------
// K1: LayerNorm(x) -> xn_bf16 ; cast q_in -> bf16.  512 blocks, 16 rows each.
// ---------------------------------------------------------------------------
__global__ __launch_bounds__(256) void k_ln(
    const float* __restrict__ x, const float* __restrict__ qin,
    const float* __restrict__ lng, const float* __restrict__ lnb,
    unsigned short* __restrict__ xn_bf, unsigned short* __restrict__ qin_bf)
{
    const int tid = threadIdx.x, lane = tid & 63, wv = tid >> 6;
    const int r0 = blockIdx.x << 4;

    #pragma unroll
    for (int u = 0; u < 4; ++u) {
        const int i4 = ((u << 8) + tid) << 2;
        const int r = i4 >> 8, c = i4 & 255;
        const f4v qv = *(const f4v*)&qin[(r0 + r) * FF + c];
        us4v o;
        #pragma unroll
        for (int j = 0; j < 4; ++j) o[j] = f2bf(qv[j]);
        *(us4v*)&qin_bf[(r0 + r) * FF + c] = o;
    }

    #pragma unroll
    for (int rr = 0; rr < 4; ++rr) {
        const int row = r0 + (wv << 2) + rr;
        float v[4], s = 0.f, s2 = 0.f;
        #pragma unroll
        for (int c4 = 0; c4 < 4; ++c4) {
            v[c4] = x[row * FF + (c4 << 6) + lane];
            s += v[c4]; s2 += v[c4] * v[c4];
        }
        #pragma unroll
        for (int off = 1; off < 64; off <<= 1) {
            s  += __shfl_xor(s, off);
            s2 += __shfl_xor(s2, off);
        }
        const float mu  = s * (1.f / FF);
        const float rsd = rsqrtf(s2 * (1.f / FF) - mu * mu + 1e-5f);
        #pragma unroll
        for (int c4 = 0; c4 < 4; ++c4) {
            const int c = (c4 << 6) + lane;
            xn_bf[row * FF + c] = f2bf((v[c4] - mu) * rsd * lng[c] + lnb[c]);
        }
    }
}

// ---------------------------------------------------------------------------
// K2: MFMA projections.  z=0: Qh = (qin@Wq + bq)*0.125 (scale folded, exact
// in bf16); z=1: Kh = xn@Wk + bk; z=2: Vt = (xn@Wv + bv)^T stored [bh][d][t]
// (computed transposed by swapping MFMA operand roles).
// Block: 64 rows x 256 cols, 4 waves each own a 64-col (= one head) slice.
// ---------------------------------------------------------------------------
__global__ __launch_bounds__(256) void k_proj(
    const unsigned short* __restrict__ qin_bf, const unsigned short* __restrict__ xn_bf,
    const unsigned short* __restrict__ Wt,
    const float* __restrict__ bq, const float* __restrict__ bk, const float* __restrict__ bv,
    unsigned short* __restrict__ Qh, unsigned short* __restrict__ Kh,
    unsigned short* __restrict__ Vt)
{
    __shared__ __align__(16) unsigned short As[64 * 264];
    const int z = blockIdx.y;
    const unsigned short* A = (z == 0) ? qin_bf : xn_bf;
    const unsigned short* W = Wt + (z << 16);
    const float* bias = (z == 0) ? bq : (z == 1) ? bk : bv;
    unsigned short* dst = (z == 0) ? Qh : (z == 1) ? Kh : Vt;
    const int tid = threadIdx.x;
    const int m0 = blockIdx.x << 6;

    #pragma unroll
    for (int u = 0; u < 8; ++u) {
        const int idx = (u << 8) + tid;
        const int r = idx >> 5, c = (idx & 31) << 3;
        *(us8v*)&As[r * 264 + c] = *(const us8v*)&A[(m0 + r) * FF + c];
    }
    __syncthreads();

    const int lane = tid & 63, nw = tid >> 6, gq = lane >> 5, l31 = lane & 31;
    f16v acc[2][2];
    #pragma unroll
    for (int i = 0; i < 2; ++i)
        #pragma unroll
        for (int j = 0; j < 2; ++j)
            #pragma unroll
            for (int e = 0; e < 16; ++e) acc[i][j][e] = 0.f;

    for (int ks = 0; ks < 16; ++ks) {
        const int k0 = (ks << 4) + (gq << 3);
        bf8v af[2], wf[2];
        af[0] = us2bf(*(const us8v*)&As[l31 * 264 + k0]);
        af[1] = us2bf(*(const us8v*)&As[(32 + l31) * 264 + k0]);
        wf[0] = us2bf(*(const us8v*)&W[((nw << 6) + l31) * FF + k0]);
        wf[1] = us2bf(*(const us8v*)&W[((nw << 6) + 32 + l31) * FF + k0]);
        if (z == 2) {
            #pragma unroll
            for (int ti = 0; ti < 2; ++ti)
                #pragma unroll
                for (int tj = 0; tj < 2; ++tj)
                    acc[ti][tj] = __builtin_amdgcn_mfma_f32_32x32x16_bf16(
                        wf[tj], af[ti], acc[ti][tj], 0, 0, 0);
        } else {
            #pragma unroll
            for (int ti = 0; ti < 2; ++ti)
                #pragma unroll
                for (int tj = 0; tj < 2; ++tj)
                    acc[ti][tj] = __builtin_amdgcn_mfma_f32_32x32x16_bf16(
                        af[ti], wf[tj], acc[ti][tj], 0, 0, 0);
        }
    }

    if (z != 2) {
        // D[m=t][n=wcol]; row=(reg&3)+8*(reg>>2)+4*gq, col=l31
        #pragma unroll
        for (int ti = 0; ti < 2; ++ti)
            #pragma unroll
            for (int tj = 0; tj < 2; ++tj)
                #pragma unroll
                for (int reg = 0; reg < 16; ++reg) {
                    const int row = (reg & 3) + ((reg >> 2) << 3) + (gq << 2);
                    const int tg = m0 + (ti << 5) + row;
                    const int n = (nw << 6) + (tj << 5) + l31;
                    float val = acc[ti][tj][reg] + bias[n];
                    if (z == 0) val *= 0.125f;
                    const int b = tg >> 10, t = tg & 1023;
                    dst[(((b << 2) + nw) << 16) + (t << 6) + (tj << 5) + l31] = f2bf(val);
                }
    } else {
        // D[m=wcol][n=t]
        #pragma unroll
        for (int ti = 0; ti < 2; ++ti)
            #pragma unroll
            for (int tj = 0; tj < 2; ++tj)
                #pragma unroll
                for (int reg = 0; reg < 16; ++reg) {
                    const int row = (reg & 3) + ((reg >> 2) << 3) + (gq << 2);
                    const int d = (tj << 5) + row;
                    const int tg = m0 + (ti << 5) + l31;
                    const float val = acc[ti][tj][reg] + bias[(nw << 6) + d];
                    const int b = tg >> 10, t = tg & 1023;
                    dst[(((b << 2) + nw) << 16) + (d << 10) + t] = f2bf(val);
                }
    }
}

// ---------------------------------------------------------------------------
// K3: relative-position term, mask + scale folded in.
// Bm[bh][ql][t] = mask[b][q][t] ? (Qh_scaled[bh][q] . posk[q][t]) : -3e38
// Qh is pre-scaled by 0.125, so the MFMA result is already the scaled bias.
// Per fixed q this is a 32x64 @ 64xT GEMM -> pos_k read from HBM exactly once.
// ---------------------------------------------------------------------------
__global__ __launch_bounds__(256) void k_bterm(
    const unsigned short* __restrict__ Qh, const float* __restrict__ posk,
    const int* __restrict__ mask, unsigned short* __restrict__ Bm, int qbase)
{
    const int tid = threadIdx.x, lane = tid & 63, wv = tid >> 6;
    const int gq = lane >> 5, m = lane & 31;
    const int ql = blockIdx.y, q = qbase + ql;

    bf8v afr[4];
    #pragma unroll
    for (int kk = 0; kk < 4; ++kk)
        afr[kk] = us2bf(*(const us8v*)&Qh[(m << 16) + (q << 6) + (kk << 4) + (gq << 3)]);

    const int t0w = (blockIdx.x << 9) + (wv << 7);
    for (int st = 0; st < 4; ++st) {
        const int t = t0w + (st << 5) + m;
        bf8v bfr[4];
        #pragma unroll
        for (int kk = 0; kk < 4; ++kk) {
            const int d0 = (kk << 4) + (gq << 3);
            const f4v p0 = *(const f4v*)&posk[(((q << 10) + t) << 6) + d0];
            const f4v p1 = *(const f4v*)&posk[(((q << 10) + t) << 6) + d0 + 4];
            bf8v bb;
            bb[0] = (__bf16)p0[0]; bb[1] = (__bf16)p0[1];
            bb[2] = (__bf16)p0[2]; bb[3] = (__bf16)p0[3];
            bb[4] = (__bf16)p1[0]; bb[5] = (__bf16)p1[1];
            bb[6] = (__bf16)p1[2]; bb[7] = (__bf16)p1[3];
            bfr[kk] = bb;
        }
        f16v acc;
        #pragma unroll
        for (int i = 0; i < 16; ++i) acc[i] = 0.f;
        #pragma unroll
        for (int kk = 0; kk < 4; ++kk)
            acc = __builtin_amdgcn_mfma_f32_32x32x16_bf16(afr[kk], bfr[kk], acc, 0, 0, 0);

        int mk[4];
        #pragma unroll
        for (int g = 0; g < 4; ++g)     // b = 2g + gq for reg group g
            mk[g] = mask[(((g << 1) + gq) << 20) + (q << 10) + t];
        #pragma unroll
        for (int reg = 0; reg < 16; ++reg) {
            const int g = reg >> 2;
            const int bhr = (reg & 3) + (g << 3) + (gq << 2);
            const float val = mk[g] ? acc[reg] : -3.0e38f;
            Bm[(bhr << 19) + (ql << 10) + t] = f2bf(val);
        }
    }
}

// ---------------------------------------------------------------------------
// K4: flash attention per (b,h, 32-q tile).  K/V fragments read directly from
// L2 (no LDS staging); Bm tile staged coalesced; mask & scale pre-folded.
// 3 barriers/iter.  Writes aout bf16 [row t][F].
// ---------------------------------------------------------------------------
__global__ __launch_bounds__(256) void k_attn(
    const unsigned short* __restrict__ Qh, const unsigned short* __restrict__ Kh,
    const unsigned short* __restrict__ Vt, const unsigned short* __restrict__ Bm,
    unsigned short* __restrict__ aout_bf, int qbase)
{
    __shared__ __align__(16) unsigned short Qs[32 * 72];
    __shared__ __align__(16) unsigned short Ps[32 * 136];
    __shared__ __align__(16) unsigned short Bs[32 * 136];
    __shared__ float m_s[32], l_s[32], wmax[4][32], wsum[4][32];

    const int tid = threadIdx.x, lane = tid & 63, wv = tid >> 6;
    const int l15 = lane & 15, quad = lane >> 4;
    const int bh = blockIdx.x & 31, qt = blockIdx.x >> 5;
    const int b = bh >> 2, h = bh & 3;
    const int q0l = qt << 5, q0g = qbase + q0l;

    if (tid < 32) { m_s[tid] = -3.0e38f; l_s[tid] = 0.f; }
    {
        const int r = tid >> 3, d0 = (tid & 7) << 3;
        *(us8v*)&Qs[r * 72 + d0] =
            *(const us8v*)&Qh[(bh << 16) + ((q0g + r) << 6) + d0];
    }

    f4v o0, o1;
    #pragma unroll
    for (int i = 0; i < 4; ++i) { o0[i] = 0.f; o1[i] = 0.f; }

    for (int it = 0; it < 8; ++it) {
        const int t0 = it << 7;
        #pragma unroll
        for (int u = 0; u < 2; ++u) {
            const int idx = (u << 8) + tid;
            const int r = idx >> 4, c = (idx & 15) << 3;
            *(us8v*)&Bs[r * 136 + c] =
                *(const us8v*)&Bm[(bh << 19) + ((q0l + r) << 10) + t0 + c];
        }
        __syncthreads();   // B1: Bs (and first-iter Qs) ready

        f4v s00, s01, s10, s11;
        #pragma unroll
        for (int i = 0; i < 4; ++i) { s00[i]=0.f; s01[i]=0.f; s10[i]=0.f; s11[i]=0.f; }
        #pragma unroll
        for (int kk = 0; kk < 2; ++kk) {
            const int d0 = (kk << 5) + (quad << 3);
            const bf8v aq0 = us2bf(*(const us8v*)&Qs[l15 * 72 + d0]);
            const bf8v aq1 = us2bf(*(const us8v*)&Qs[(16 + l15) * 72 + d0]);
            const bf8v kb0 = us2bf(*(const us8v*)&Kh[(bh << 16) + ((t0 + (wv << 5) + l15) << 6) + d0]);
            const bf8v kb1 = us2bf(*(const us8v*)&Kh[(bh << 16) + ((t0 + (wv << 5) + 16 + l15) << 6) + d0]);
            s00 = __builtin_amdgcn_mfma_f32_16x16x32_bf16(aq0, kb0, s00, 0, 0, 0);
            s01 = __builtin_amdgcn_mfma_f32_16x16x32_bf16(aq0, kb1, s01, 0, 0, 0);
            s10 = __builtin_amdgcn_mfma_f32_16x16x32_bf16(aq1, kb0, s10, 0, 0, 0);
            s11 = __builtin_amdgcn_mfma_f32_16x16x32_bf16(aq1, kb1, s11, 0, 0, 0);
        }

        float sv[2][2][4];
        #pragma unroll
        for (int mf = 0; mf < 2; ++mf)
            #pragma unroll
            for (int nf = 0; nf < 2; ++nf) {
                const f4v sfr = (mf == 0) ? (nf == 0 ? s00 : s01)
                                          : (nf == 0 ? s10 : s11);
                const int tl = (wv << 5) + (nf << 4) + l15;
                #pragma unroll
                for (int r = 0; r < 4; ++r) {
                    const int q = (mf << 4) + (quad << 2) + r;
                    sv[mf][nf][r] = sfr[r] + bf2f(Bs[q * 136 + tl]);
                }
            }

        float rmax[2][4];
        #pragma unroll
        for (int mf = 0; mf < 2; ++mf)
            #pragma unroll
            for (int r = 0; r < 4; ++r) {
                float vx = fmaxf(sv[mf][0][r], sv[mf][1][r]);
                vx = fmaxf(vx, __shfl_xor(vx, 1));
                vx = fmaxf(vx, __shfl_xor(vx, 2));
                vx = fmaxf(vx, __shfl_xor(vx, 4));
                vx = fmaxf(vx, __shfl_xor(vx, 8));
                rmax[mf][r] = vx;
            }
        if (l15 == 0) {
            #pragma unroll
            for (int mf = 0; mf < 2; ++mf)
                #pragma unroll
                for (int r = 0; r < 4; ++r)
                    wmax[wv][(mf << 4) + (quad << 2) + r] = rmax[mf][r];
        }
        __syncthreads();   // B2: wmax ready

        float alpha[2][4], mnew[2][4];
        #pragma unroll
        for (int mf = 0; mf < 2; ++mf)
            #pragma unroll
            for (int r = 0; r < 4; ++r) {
                const int q = (mf << 4) + (quad << 2) + r;
                const float tm = fmaxf(fmaxf(wmax[0][q], wmax[1][q]),
                                       fmaxf(wmax[2][q], wmax[3][q]));
                const float mo = m_s[q];
                const float mn = fmaxf(mo, tm);
                mnew[mf][r]  = mn;
                alpha[mf][r] = __expf(mo - mn);
            }
        #pragma unroll
        for (int mf = 0; mf < 2; ++mf)
            #pragma unroll
            for (int r = 0; r < 4; ++r) {
                const int q = (mf << 4) + (quad << 2) + r;
                const float p0 = __expf(sv[mf][0][r] - mnew[mf][r]);
                const float p1 = __expf(sv[mf][1][r] - mnew[mf][r]);
                Ps[q * 136 + (wv << 5) + l15]      = f2bf(p0);
                Ps[q * 136 + (wv << 5) + 16 + l15] = f2bf(p1);
                float rs2 = p0 + p1;
                rs2 += __shfl_xor(rs2, 1);
                rs2 += __shfl_xor(rs2, 2);
                rs2 += __shfl_xor(rs2, 4);
                rs2 += __shfl_xor(rs2, 8);
                if (l15 == 0) wsum[wv][q] = rs2;
            }
        #pragma unroll
        for (int r = 0; r < 4; ++r) { o0[r] *= alpha[0][r]; o1[r] *= alpha[1][r]; }
        __syncthreads();   // B3: Ps ready

        if (tid < 32) {
            const int q = tid;
            const float tm = fmaxf(fmaxf(wmax[0][q], wmax[1][q]),
                                   fmaxf(wmax[2][q], wmax[3][q]));
            const float mo = m_s[q];
            const float mn = fmaxf(mo, tm);
            l_s[q] = l_s[q] * __expf(mo - mn)
                   + (wsum[0][q] + wsum[1][q]) + (wsum[2][q] + wsum[3][q]);
            m_s[q] = mn;
        }

        // PV: A from Ps (LDS b128), B direct from global Vt[bh][d][t]
        #pragma unroll
        for (int kk = 0; kk < 4; ++kk) {
            const int toff = (kk << 5) + (quad << 3);
            const bf8v vbf = us2bf(*(const us8v*)&Vt[(bh << 16) + (((wv << 4) + l15) << 10) + t0 + toff]);
            const bf8v ap0 = us2bf(*(const us8v*)&Ps[l15 * 136 + toff]);
            const bf8v ap1 = us2bf(*(const us8v*)&Ps[(16 + l15) * 136 + toff]);
            o0 = __builtin_amdgcn_mfma_f32_16x16x32_bf16(ap0, vbf, o0, 0, 0, 0);
            o1 = __builtin_amdgcn_mfma_f32_16x16x32_bf16(ap1, vbf, o1, 0, 0, 0);
        }
        // no loop-end barrier: next iteration's B1 provides the separation
    }
    __syncthreads();

    const int d = (wv << 4) + l15;
    #pragma unroll
    for (int mf = 0; mf < 2; ++mf)
        #pragma unroll
        for (int r = 0; r < 4; ++r) {
            const int q = (mf << 4) + (quad << 2) + r;
            const float ov = ((mf == 0) ? o0[r] : o1[r]) / l_s[q];
            aout_bf[((b << 10) + q0g + q) * FF + (h << 6) + d] = f2bf(ov);
        }
}

// ---------------------------------------------------------------------------
// K5: out = aout @ Wo + bo  (MFMA, fp32 output)
// ---------------------------------------------------------------------------
__global__ __launch_bounds__(256) void k_oproj(
    const unsigned short* __restrict__ aout_bf, const unsigned short* __restrict__ Wot,
    const float* __restrict__ bo, float* __restrict__ out)
{
    __shared__ __align__(16) unsigned short As[64 * 264];
    const int tid = threadIdx.x;
    const int m0 = blockIdx.x << 6;

    #pragma unroll
    for (int u = 0; u < 8; ++u) {
        const int idx = (u << 8) + tid;
        const int r = idx >> 5, c = (idx & 31) << 3;
        *(us8v*)&As[r * 264 + c] = *(const us8v*)&aout_bf[(m0 + r) * FF + c];
    }
    __syncthreads();

    const int lane = tid & 63, nw = tid >> 6, gq = lane >> 5, l31 = lane & 31;
    f16v acc[2][2];
    #pragma unroll
    for (int i = 0; i < 2; ++i)
        #pragma unroll
        for (int j = 0; j < 2; ++j)
            #pragma unroll
            for (int e = 0; e < 16; ++e) acc[i][j][e] = 0.f;

    for (int ks = 0; ks < 16; ++ks) {
        const int k0 = (ks << 4) + (gq << 3);
        bf8v af[2], wf[2];
        af[0] = us2bf(*(const us8v*)&As[l31 * 264 + k0]);
        af[1] = us2bf(*(const us8v*)&As[(32 + l31) * 264 + k0]);
        wf[0] = us2bf(*(const us8v*)&Wot[((nw << 6) + l31) * FF + k0]);
        wf[1] = us2bf(*(const us8v*)&Wot[((nw << 6) + 32 + l31) * FF + k0]);
        #pragma unroll
        for (int ti = 0; ti < 2; ++ti)
            #pragma unroll
            for (int tj = 0; tj < 2; ++tj)
                acc[ti][tj] = __builtin_amdgcn_mfma_f32_32x32x16_bf16(
                    af[ti], wf[tj], acc[ti][tj], 0, 0, 0);
    }

    #pragma unroll
    for (int ti = 0; ti < 2; ++ti)
        #pragma unroll
        for (int tj = 0; tj < 2; ++tj)
            #pragma unroll
            for (int reg = 0; reg < 16; ++reg) {
                const int row = (reg & 3) + ((reg >> 2) << 3) + (gq << 2);
                const int tg = m0 + (ti << 5) + row;
                const int n = (nw << 6) + (tj << 5) + l31;
                out[tg * FF + n] = acc[ti][tj][reg] + bo[n];
            }
}

// ---------------------------------------------------------------------------
// ws layout (MB): Wt 0..0.5 | qin_bf @1 | xn_bf @5 | Qh @9 | Kh @13 |
// Vt @17 | aout_bf @21 | Bm(half) @25..57.
// ---------------------------------------------------------------------------
extern "C" void kernel_launch(void* const* d_in, const int* in_sizes, int n_in,
                              void* d_out, int out_size, void* d_ws, size_t ws_size,
                              hipStream_t stream)
{
    const float* x    = (const float*)d_in[0];
    const float* qin  = (const float*)d_in[1];
    const float* posk = (const float*)d_in[2];
    const int*   mask = (const int*)d_in[3];
    const float* ln_g = (const float*)d_in[4];
    const float* ln_b = (const float*)d_in[5];
    const float* Wq   = (const float*)d_in[6];
    const float* bq   = (const float*)d_in[7];
    const float* Wk   = (const float*)d_in[8];
    const float* bk   = (const float*)d_in[9];
    const float* Wv   = (const float*)d_in[10];
    const float* bv   = (const float*)d_in[11];
    const float* Wo   = (const float*)d_in[12];
    const float* bo   = (const float*)d_in[13];
    float* out = (float*)d_out;

    char* ws = (char*)d_ws;
    unsigned short* wWt   = (unsigned short*)(ws);
    unsigned short* qinb  = (unsigned short*)(ws + (size_t)(1u << 20));
    unsigned short* xnb   = (unsigned short*)(ws + (size_t)(5u << 20));
    unsigned short* Qh    = (unsigned short*)(ws + (size_t)(9u << 20));
    unsigned short* Kh    = (unsigned short*)(ws + (size_t)(13u << 20));
    unsigned short* Vth   = (unsigned short*)(ws + (size_t)(17u << 20));
    unsigned short* aoutb = (unsigned short*)(ws + (size_t)(21u << 20));
    unsigned short* Bm    = (unsigned short*)(ws + (size_t)(25u << 20));

    hipLaunchKernelGGL(k_wprep, dim3(64, 4), dim3(256), 0, stream, Wq, Wk, Wv, Wo, wWt);
    hipLaunchKernelGGL(k_ln, dim3(512), dim3(256), 0, stream,
                       x, qin, ln_g, ln_b, xnb, qinb);
    hipLaunchKernelGGL(k_proj, dim3(128, 3), dim3(256), 0, stream,
                       qinb, xnb, wWt, bq, bk, bv, Qh, Kh, Vth);
    for (int half = 0; half < 2; ++half) {
        const int qbase = half * 512;
        hipLaunchKernelGGL(k_bterm, dim3(2, 512), dim3(256), 0, stream,
                           Qh, posk, mask, Bm, qbase);
        hipLaunchKernelGGL(k_attn, dim3(512), dim3(256), 0, stream,
                           Qh, Kh, Vth, Bm, aoutb, qbase);
    }
    hipLaunchKernelGGL(k_oproj, dim3(128), dim3(256), 0, stream,
                       aoutb, wWt + (3 << 16), bo, out);
}

// Round 3
// 533.251 us; speedup vs baseline: 1.4831x; 1.0058x over previous
//
#include <hip/hip_runtime.h>
#include <hip/hip_bf16.h>

#define TT 1024
#define FF 256

typedef float  f4v  __attribute__((ext_vector_type(4)));
typedef float  f16v __attribute__((ext_vector_type(16)));
typedef __bf16 bf8v __attribute__((ext_vector_type(8)));
typedef unsigned short us8v __attribute__((ext_vector_type(8)));
typedef unsigned short us4v __attribute__((ext_vector_type(4)));

static __device__ __forceinline__ unsigned short f2bf(float x) {
    return __builtin_bit_cast(unsigned short, (__bf16)x);
}
static __device__ __forceinline__ float bf2f(unsigned short u) {
    return (float)__builtin_bit_cast(__bf16, u);
}
static __device__ __forceinline__ bf8v us2bf(us8v v) {
    return __builtin_bit_cast(bf8v, v);
}

// ---------------------------------------------------------------------------
// K0: weight prep — W[k][n] fp32 -> Wt[n][k] bf16, 4 matrices (Q,K,V,O).
// ---------------------------------------------------------------------------
__global__ __launch_bounds__(256) void k_wprep(
    const float* __restrict__ Wq, const float* __restrict__ Wk,
    const float* __restrict__ Wv, const float* __restrict__ Wo,
    unsigned short* __restrict__ Wt)
{
    __shared__ unsigned short T[32][36];
    const float* W = (blockIdx.y == 0) ? Wq : (blockIdx.y == 1) ? Wk
                   : (blockIdx.y == 2) ? Wv : Wo;
    unsigned short* dst = Wt + (blockIdx.y << 16);
    const int kt = (blockIdx.x >> 3) << 5, nt = (blockIdx.x & 7) << 5;
    const int r = threadIdx.x >> 3, c0 = (threadIdx.x & 7) << 2;
    const f4v w = *(const f4v*)&W[(kt + r) * FF + nt + c0];
    #pragma unroll
    for (int j = 0; j < 4; ++j) T[c0 + j][r] = f2bf(w[j]);
    __syncthreads();
    *(us4v*)&dst[(nt + r) * FF + kt + c0] = *(const us4v*)&T[r][c0];
}

// ---------------------------------------------------------------------------
// K1: LayerNorm(x) -> xn_bf16 ; cast q_in -> bf16.
// ---------------------------------------------------------------------------
__global__ __launch_bounds__(256) void k_ln(
    const float* __restrict__ x, const float* __restrict__ qin,
    const float* __restrict__ lng, const float* __restrict__ lnb,
    unsigned short* __restrict__ xn_bf, unsigned short* __restrict__ qin_bf)
{
    const int tid = threadIdx.x, lane = tid & 63, wv = tid >> 6;
    const int r0 = blockIdx.x << 4;

    #pragma unroll
    for (int u = 0; u < 4; ++u) {
        const int i4 = ((u << 8) + tid) << 2;
        const int r = i4 >> 8, c = i4 & 255;
        const f4v qv = *(const f4v*)&qin[(r0 + r) * FF + c];
        us4v o;
        #pragma unroll
        for (int j = 0; j < 4; ++j) o[j] = f2bf(qv[j]);
        *(us4v*)&qin_bf[(r0 + r) * FF + c] = o;
    }

    #pragma unroll
    for (int rr = 0; rr < 4; ++rr) {
        const int row = r0 + (wv << 2) + rr;
        float v[4], s = 0.f, s2 = 0.f;
        #pragma unroll
        for (int c4 = 0; c4 < 4; ++c4) {
            v[c4] = x[row * FF + (c4 << 6) + lane];
            s += v[c4]; s2 += v[c4] * v[c4];
        }
        #pragma unroll
        for (int off = 1; off < 64; off <<= 1) {
            s  += __shfl_xor(s, off);
            s2 += __shfl_xor(s2, off);
        }
        const float mu  = s * (1.f / FF);
        const float rsd = rsqrtf(s2 * (1.f / FF) - mu * mu + 1e-5f);
        #pragma unroll
        for (int c4 = 0; c4 < 4; ++c4) {
            const int c = (c4 << 6) + lane;
            xn_bf[row * FF + c] = f2bf((v[c4] - mu) * rsd * lng[c] + lnb[c]);
        }
    }
}

// ---------------------------------------------------------------------------
// K2: MFMA projections.  z=0: Qh = (qin@Wq + bq)*0.125; z=1: Kh = xn@Wk + bk;
// z=2: Vt = (xn@Wv + bv)^T stored [bh][d][t].
// ---------------------------------------------------------------------------
__global__ __launch_bounds__(256) void k_proj(
    const unsigned short* __restrict__ qin_bf, const unsigned short* __restrict__ xn_bf,
    const unsigned short* __restrict__ Wt,
    const float* __restrict__ bq, const float* __restrict__ bk, const float* __restrict__ bv,
    unsigned short* __restrict__ Qh, unsigned short* __restrict__ Kh,
    unsigned short* __restrict__ Vt)
{
    __shared__ __align__(16) unsigned short As[64 * 264];
    const int z = blockIdx.y;
    const unsigned short* A = (z == 0) ? qin_bf : xn_bf;
    const unsigned short* W = Wt + (z << 16);
    const float* bias = (z == 0) ? bq : (z == 1) ? bk : bv;
    unsigned short* dst = (z == 0) ? Qh : (z == 1) ? Kh : Vt;
    const int tid = threadIdx.x;
    const int m0 = blockIdx.x << 6;

    #pragma unroll
    for (int u = 0; u < 8; ++u) {
        const int idx = (u << 8) + tid;
        const int r = idx >> 5, c = (idx & 31) << 3;
        *(us8v*)&As[r * 264 + c] = *(const us8v*)&A[(m0 + r) * FF + c];
    }
    __syncthreads();

    const int lane = tid & 63, nw = tid >> 6, gq = lane >> 5, l31 = lane & 31;
    f16v acc[2][2];
    #pragma unroll
    for (int i = 0; i < 2; ++i)
        #pragma unroll
        for (int j = 0; j < 2; ++j)
            #pragma unroll
            for (int e = 0; e < 16; ++e) acc[i][j][e] = 0.f;

    for (int ks = 0; ks < 16; ++ks) {
        const int k0 = (ks << 4) + (gq << 3);
        bf8v af[2], wf[2];
        af[0] = us2bf(*(const us8v*)&As[l31 * 264 + k0]);
        af[1] = us2bf(*(const us8v*)&As[(32 + l31) * 264 + k0]);
        wf[0] = us2bf(*(const us8v*)&W[((nw << 6) + l31) * FF + k0]);
        wf[1] = us2bf(*(const us8v*)&W[((nw << 6) + 32 + l31) * FF + k0]);
        if (z == 2) {
            #pragma unroll
            for (int ti = 0; ti < 2; ++ti)
                #pragma unroll
                for (int tj = 0; tj < 2; ++tj)
                    acc[ti][tj] = __builtin_amdgcn_mfma_f32_32x32x16_bf16(
                        wf[tj], af[ti], acc[ti][tj], 0, 0, 0);
        } else {
            #pragma unroll
            for (int ti = 0; ti < 2; ++ti)
                #pragma unroll
                for (int tj = 0; tj < 2; ++tj)
                    acc[ti][tj] = __builtin_amdgcn_mfma_f32_32x32x16_bf16(
                        af[ti], wf[tj], acc[ti][tj], 0, 0, 0);
        }
    }

    if (z != 2) {
        #pragma unroll
        for (int ti = 0; ti < 2; ++ti)
            #pragma unroll
            for (int tj = 0; tj < 2; ++tj)
                #pragma unroll
                for (int reg = 0; reg < 16; ++reg) {
                    const int row = (reg & 3) + ((reg >> 2) << 3) + (gq << 2);
                    const int tg = m0 + (ti << 5) + row;
                    const int n = (nw << 6) + (tj << 5) + l31;
                    float val = acc[ti][tj][reg] + bias[n];
                    if (z == 0) val *= 0.125f;
                    const int b = tg >> 10, t = tg & 1023;
                    dst[(((b << 2) + nw) << 16) + (t << 6) + (tj << 5) + l31] = f2bf(val);
                }
    } else {
        #pragma unroll
        for (int ti = 0; ti < 2; ++ti)
            #pragma unroll
            for (int tj = 0; tj < 2; ++tj)
                #pragma unroll
                for (int reg = 0; reg < 16; ++reg) {
                    const int row = (reg & 3) + ((reg >> 2) << 3) + (gq << 2);
                    const int d = (tj << 5) + row;
                    const int tg = m0 + (ti << 5) + l31;
                    const float val = acc[ti][tj][reg] + bias[(nw << 6) + d];
                    const int b = tg >> 10, t = tg & 1023;
                    dst[(((b << 2) + nw) << 16) + (d << 10) + t] = f2bf(val);
                }
    }
}

// ---------------------------------------------------------------------------
// K3: relative-position term with mask+scale folded.  One t-tile of 32 per
// wave, grid (8, 1024): blockIdx.y = q, blockIdx.x covers t in 128-chunks.
// Bm[bh][q][t] = mask ? Qh_scaled[bh][q].posk[q][t] : -3e38  (bf16)
// ---------------------------------------------------------------------------
__global__ __launch_bounds__(256) void k_bterm(
    const unsigned short* __restrict__ Qh, const float* __restrict__ posk,
    const int* __restrict__ mask, unsigned short* __restrict__ Bm)
{
    const int tid = threadIdx.x, lane = tid & 63, wv = tid >> 6;
    const int gq = lane >> 5, m = lane & 31;
    const int q = blockIdx.y;
    const int t = (blockIdx.x << 7) + (wv << 5) + m;

    bf8v afr[4];
    #pragma unroll
    for (int kk = 0; kk < 4; ++kk)
        afr[kk] = us2bf(*(const us8v*)&Qh[(m << 16) + (q << 6) + (kk << 4) + (gq << 3)]);

    bf8v bfr[4];
    #pragma unroll
    for (int kk = 0; kk < 4; ++kk) {
        const int d0 = (kk << 4) + (gq << 3);
        const f4v p0 = *(const f4v*)&posk[(((q << 10) + t) << 6) + d0];
        const f4v p1 = *(const f4v*)&posk[(((q << 10) + t) << 6) + d0 + 4];
        bf8v bb;
        bb[0] = (__bf16)p0[0]; bb[1] = (__bf16)p0[1];
        bb[2] = (__bf16)p0[2]; bb[3] = (__bf16)p0[3];
        bb[4] = (__bf16)p1[0]; bb[5] = (__bf16)p1[1];
        bb[6] = (__bf16)p1[2]; bb[7] = (__bf16)p1[3];
        bfr[kk] = bb;
    }

    f16v acc;
    #pragma unroll
    for (int i = 0; i < 16; ++i) acc[i] = 0.f;
    #pragma unroll
    for (int kk = 0; kk < 4; ++kk)
        acc = __builtin_amdgcn_mfma_f32_32x32x16_bf16(afr[kk], bfr[kk], acc, 0, 0, 0);

    int mk[4];
    #pragma unroll
    for (int g = 0; g < 4; ++g)   // b = 2g + gq for reg group g
        mk[g] = mask[(((g << 1) + gq) << 20) + (q << 10) + t];
    #pragma unroll
    for (int reg = 0; reg < 16; ++reg) {
        const int g = reg >> 2;
        const int bhr = (reg & 3) + (g << 3) + (gq << 2);
        const float val = mk[g] ? acc[reg] : -3.0e38f;
        Bm[(bhr << 20) + (q << 10) + t] = f2bf(val);
    }
}

// ---------------------------------------------------------------------------
// K4: flash attention per (b,h, 32-q tile).  Single launch, grid 1024,
// XCD-aware bh swizzle.  2 barriers/iter, double-buffered Bm tile (register
// prefetch), softmax m/l state in registers (all waves hold identical copies;
// wsum fold deferred one iteration so all LDS has clean barrier separation).
// ---------------------------------------------------------------------------
__global__ __launch_bounds__(256, 4) void k_attn(
    const unsigned short* __restrict__ Qh, const unsigned short* __restrict__ Kh,
    const unsigned short* __restrict__ Vt, const unsigned short* __restrict__ Bm,
    unsigned short* __restrict__ aout_bf)
{
    __shared__ __align__(16) unsigned short Qs[32 * 72];
    __shared__ __align__(16) unsigned short Ps[32 * 136];
    __shared__ __align__(16) unsigned short Bs[2][32 * 136];
    __shared__ float wmax[4][32], wsum[4][32];

    const int tid = threadIdx.x, lane = tid & 63, wv = tid >> 6;
    const int l15 = lane & 15, quad = lane >> 4;
    const int blk = blockIdx.x;
    const int bh = ((blk & 7) << 2) | ((blk >> 3) & 3);  // same bh -> same XCD
    const int qt = blk >> 5;
    const int b = bh >> 2, h = bh & 3;
    const int q0 = qt << 5;

    {   // Q tile once
        const int r = tid >> 3, d0 = (tid & 7) << 3;
        *(us8v*)&Qs[r * 72 + d0] =
            *(const us8v*)&Qh[(bh << 16) + ((q0 + r) << 6) + d0];
    }
    {   // Bs[0]
        #pragma unroll
        for (int u = 0; u < 2; ++u) {
            const int idx = (u << 8) + tid;
            const int r = idx >> 4, c = (idx & 15) << 3;
            *(us8v*)&Bs[0][r * 136 + c] =
                *(const us8v*)&Bm[(bh << 20) + ((q0 + r) << 10) + c];
        }
    }
    __syncthreads();

    f4v o0, o1;
    float mreg[2][4], lreg[2][4], alpha[2][4];
    #pragma unroll
    for (int i = 0; i < 4; ++i) { o0[i] = 0.f; o1[i] = 0.f; }
    #pragma unroll
    for (int mf = 0; mf < 2; ++mf)
        #pragma unroll
        for (int r = 0; r < 4; ++r) { mreg[mf][r] = -3.0e38f; lreg[mf][r] = 0.f; }

    for (int it = 0; it < 8; ++it) {
        const int t0 = it << 7;
        const int cur = it & 1;

        // prefetch next Bm tile into regs (no barrier dependence)
        us8v pf[2];
        if (it < 7) {
            #pragma unroll
            for (int u = 0; u < 2; ++u) {
                const int idx = (u << 8) + tid;
                const int r = idx >> 4, c = (idx & 15) << 3;
                pf[u] = *(const us8v*)&Bm[(bh << 20) + ((q0 + r) << 10) + t0 + 128 + c];
            }
        }

        // fold previous iteration's wsum into lreg (B2/B3 separate all uses)
        if (it > 0) {
            #pragma unroll
            for (int mf = 0; mf < 2; ++mf)
                #pragma unroll
                for (int r = 0; r < 4; ++r) {
                    const int q = (mf << 4) + (quad << 2) + r;
                    lreg[mf][r] += (wsum[0][q] + wsum[1][q]) + (wsum[2][q] + wsum[3][q]);
                }
        }

        // S = Q K^T (K fragments straight from L2)
        f4v s00, s01, s10, s11;
        #pragma unroll
        for (int i = 0; i < 4; ++i) { s00[i]=0.f; s01[i]=0.f; s10[i]=0.f; s11[i]=0.f; }
        #pragma unroll
        for (int kk = 0; kk < 2; ++kk) {
            const int d0 = (kk << 5) + (quad << 3);
            const bf8v aq0 = us2bf(*(const us8v*)&Qs[l15 * 72 + d0]);
            const bf8v aq1 = us2bf(*(const us8v*)&Qs[(16 + l15) * 72 + d0]);
            const bf8v kb0 = us2bf(*(const us8v*)&Kh[(bh << 16) + ((t0 + (wv << 5) + l15) << 6) + d0]);
            const bf8v kb1 = us2bf(*(const us8v*)&Kh[(bh << 16) + ((t0 + (wv << 5) + 16 + l15) << 6) + d0]);
            s00 = __builtin_amdgcn_mfma_f32_16x16x32_bf16(aq0, kb0, s00, 0, 0, 0);
            s01 = __builtin_amdgcn_mfma_f32_16x16x32_bf16(aq0, kb1, s01, 0, 0, 0);
            s10 = __builtin_amdgcn_mfma_f32_16x16x32_bf16(aq1, kb0, s10, 0, 0, 0);
            s11 = __builtin_amdgcn_mfma_f32_16x16x32_bf16(aq1, kb1, s11, 0, 0, 0);
        }

        float sv[2][2][4];
        #pragma unroll
        for (int mf = 0; mf < 2; ++mf)
            #pragma unroll
            for (int nf = 0; nf < 2; ++nf) {
                const f4v sfr = (mf == 0) ? (nf == 0 ? s00 : s01)
                                          : (nf == 0 ? s10 : s11);
                const int tl = (wv << 5) + (nf << 4) + l15;
                #pragma unroll
                for (int r = 0; r < 4; ++r) {
                    const int q = (mf << 4) + (quad << 2) + r;
                    sv[mf][nf][r] = sfr[r] + bf2f(Bs[cur][q * 136 + tl]);
                }
            }

        // per-wave row maxes -> wmax
        #pragma unroll
        for (int mf = 0; mf < 2; ++mf)
            #pragma unroll
            for (int r = 0; r < 4; ++r) {
                float vx = fmaxf(sv[mf][0][r], sv[mf][1][r]);
                vx = fmaxf(vx, __shfl_xor(vx, 1));
                vx = fmaxf(vx, __shfl_xor(vx, 2));
                vx = fmaxf(vx, __shfl_xor(vx, 4));
                vx = fmaxf(vx, __shfl_xor(vx, 8));
                if (l15 == 0) wmax[wv][(mf << 4) + (quad << 2) + r] = vx;
            }
        // stage next Bs from prefetch regs
        if (it < 7) {
            #pragma unroll
            for (int u = 0; u < 2; ++u) {
                const int idx = (u << 8) + tid;
                const int r = idx >> 4, c = (idx & 15) << 3;
                *(us8v*)&Bs[cur ^ 1][r * 136 + c] = pf[u];
            }
        }
        __syncthreads();   // B2: wmax + Bs[next] ready

        #pragma unroll
        for (int mf = 0; mf < 2; ++mf)
            #pragma unroll
            for (int r = 0; r < 4; ++r) {
                const int q = (mf << 4) + (quad << 2) + r;
                const float tm = fmaxf(fmaxf(wmax[0][q], wmax[1][q]),
                                       fmaxf(wmax[2][q], wmax[3][q]));
                const float mo = mreg[mf][r];
                const float mn = fmaxf(mo, tm);
                alpha[mf][r] = __expf(mo - mn);
                mreg[mf][r] = mn;
            }
        #pragma unroll
        for (int mf = 0; mf < 2; ++mf)
            #pragma unroll
            for (int r = 0; r < 4; ++r) {
                const int q = (mf << 4) + (quad << 2) + r;
                const float p0 = __expf(sv[mf][0][r] - mreg[mf][r]);
                const float p1 = __expf(sv[mf][1][r] - mreg[mf][r]);
                Ps[q * 136 + (wv << 5) + l15]      = f2bf(p0);
                Ps[q * 136 + (wv << 5) + 16 + l15] = f2bf(p1);
                float rs2 = p0 + p1;
                rs2 += __shfl_xor(rs2, 1);
                rs2 += __shfl_xor(rs2, 2);
                rs2 += __shfl_xor(rs2, 4);
                rs2 += __shfl_xor(rs2, 8);
                if (l15 == 0) wsum[wv][q] = rs2;
            }
        #pragma unroll
        for (int r = 0; r < 4; ++r) { o0[r] *= alpha[0][r]; o1[r] *= alpha[1][r]; }
        #pragma unroll
        for (int mf = 0; mf < 2; ++mf)
            #pragma unroll
            for (int r = 0; r < 4; ++r) lreg[mf][r] *= alpha[mf][r];
        __syncthreads();   // B3: Ps ready

        // PV: A from Ps (LDS b128), B direct from L2 Vt[bh][d][t]
        #pragma unroll
        for (int kk = 0; kk < 4; ++kk) {
            const int toff = (kk << 5) + (quad << 3);
            const bf8v vbf = us2bf(*(const us8v*)&Vt[(bh << 16) + (((wv << 4) + l15) << 10) + t0 + toff]);
            const bf8v ap0 = us2bf(*(const us8v*)&Ps[l15 * 136 + toff]);
            const bf8v ap1 = us2bf(*(const us8v*)&Ps[(16 + l15) * 136 + toff]);
            o0 = __builtin_amdgcn_mfma_f32_16x16x32_bf16(ap0, vbf, o0, 0, 0, 0);
            o1 = __builtin_amdgcn_mfma_f32_16x16x32_bf16(ap1, vbf, o1, 0, 0, 0);
        }
    }

    // final wsum fold (written pre-B3 of last iter; stable now)
    #pragma unroll
    for (int mf = 0; mf < 2; ++mf)
        #pragma unroll
        for (int r = 0; r < 4; ++r) {
            const int q = (mf << 4) + (quad << 2) + r;
            lreg[mf][r] += (wsum[0][q] + wsum[1][q]) + (wsum[2][q] + wsum[3][q]);
        }

    const int d = (wv << 4) + l15;
    #pragma unroll
    for (int mf = 0; mf < 2; ++mf)
        #pragma unroll
        for (int r = 0; r < 4; ++r) {
            const int q = (mf << 4) + (quad << 2) + r;
            const float ov = ((mf == 0) ? o0[r] : o1[r]) / lreg[mf][r];
            aout_bf[((b << 10) + q0 + q) * FF + (h << 6) + d] = f2bf(ov);
        }
}

// ---------------------------------------------------------------------------
// K5: out = aout @ Wo + bo  (MFMA, fp32 output)
// ---------------------------------------------------------------------------
__global__ __launch_bounds__(256) void k_oproj(
    const unsigned short* __restrict__ aout_bf, const unsigned short* __restrict__ Wot,
    const float* __restrict__ bo, float* __restrict__ out)
{
    __shared__ __align__(16) unsigned short As[64 * 264];
    const int tid = threadIdx.x;
    const int m0 = blockIdx.x << 6;

    #pragma unroll
    for (int u = 0; u < 8; ++u) {
        const int idx = (u << 8) + tid;
        const int r = idx >> 5, c = (idx & 31) << 3;
        *(us8v*)&As[r * 264 + c] = *(const us8v*)&aout_bf[(m0 + r) * FF + c];
    }
    __syncthreads();

    const int lane = tid & 63, nw = tid >> 6, gq = lane >> 5, l31 = lane & 31;
    f16v acc[2][2];
    #pragma unroll
    for (int i = 0; i < 2; ++i)
        #pragma unroll
        for (int j = 0; j < 2; ++j)
            #pragma unroll
            for (int e = 0; e < 16; ++e) acc[i][j][e] = 0.f;

    for (int ks = 0; ks < 16; ++ks) {
        const int k0 = (ks << 4) + (gq << 3);
        bf8v af[2], wf[2];
        af[0] = us2bf(*(const us8v*)&As[l31 * 264 + k0]);
        af[1] = us2bf(*(const us8v*)&As[(32 + l31) * 264 + k0]);
        wf[0] = us2bf(*(const us8v*)&Wot[((nw << 6) + l31) * FF + k0]);
        wf[1] = us2bf(*(const us8v*)&Wot[((nw << 6) + 32 + l31) * FF + k0]);
        #pragma unroll
        for (int ti = 0; ti < 2; ++ti)
            #pragma unroll
            for (int tj = 0; tj < 2; ++tj)
                acc[ti][tj] = __builtin_amdgcn_mfma_f32_32x32x16_bf16(
                    af[ti], wf[tj], acc[ti][tj], 0, 0, 0);
    }

    #pragma unroll
    for (int ti = 0; ti < 2; ++ti)
        #pragma unroll
        for (int tj = 0; tj < 2; ++tj)
            #pragma unroll
            for (int reg = 0; reg < 16; ++reg) {
                const int row = (reg & 3) + ((reg >> 2) << 3) + (gq << 2);
                const int tg = m0 + (ti << 5) + row;
                const int n = (nw << 6) + (tj << 5) + l31;
                out[tg * FF + n] = acc[ti][tj][reg] + bo[n];
            }
}

// ---------------------------------------------------------------------------
// ws layout (MB): Wt 0..0.5 | qin_bf @1 | xn_bf @5 | Qh @9 | Kh @13 |
// Vt @17 | aout_bf @21 | Bm (full 32x1024x1024 bf16 = 64MB) @25..89.
// ---------------------------------------------------------------------------
extern "C" void kernel_launch(void* const* d_in, const int* in_sizes, int n_in,
                              void* d_out, int out_size, void* d_ws, size_t ws_size,
                              hipStream_t stream)
{
    const float* x    = (const float*)d_in[0];
    const float* qin  = (const float*)d_in[1];
    const float* posk = (const float*)d_in[2];
    const int*   mask = (const int*)d_in[3];
    const float* ln_g = (const float*)d_in[4];
    const float* ln_b = (const float*)d_in[5];
    const float* Wq   = (const float*)d_in[6];
    const float* bq   = (const float*)d_in[7];
    const float* Wk   = (const float*)d_in[8];
    const float* bk   = (const float*)d_in[9];
    const float* Wv   = (const float*)d_in[10];
    const float* bv   = (const float*)d_in[11];
    const float* Wo   = (const float*)d_in[12];
    const float* bo   = (const float*)d_in[13];
    float* out = (float*)d_out;

    char* ws = (char*)d_ws;
    unsigned short* wWt   = (unsigned short*)(ws);
    unsigned short* qinb  = (unsigned short*)(ws + (size_t)(1u << 20));
    unsigned short* xnb   = (unsigned short*)(ws + (size_t)(5u << 20));
    unsigned short* Qh    = (unsigned short*)(ws + (size_t)(9u << 20));
    unsigned short* Kh    = (unsigned short*)(ws + (size_t)(13u << 20));
    unsigned short* Vth   = (unsigned short*)(ws + (size_t)(17u << 20));
    unsigned short* aoutb = (unsigned short*)(ws + (size_t)(21u << 20));
    unsigned short* Bm    = (unsigned short*)(ws + (size_t)(25u << 20));

    hipLaunchKernelGGL(k_wprep, dim3(64, 4), dim3(256), 0, stream, Wq, Wk, Wv, Wo, wWt);
    hipLaunchKernelGGL(k_ln, dim3(512), dim3(256), 0, stream,
                       x, qin, ln_g, ln_b, xnb, qinb);
    hipLaunchKernelGGL(k_proj, dim3(128, 3), dim3(256), 0, stream,
                       qinb, xnb, wWt, bq, bk, bv, Qh, Kh, Vth);
    hipLaunchKernelGGL(k_bterm, dim3(8, 1024), dim3(256), 0, stream,
                       Qh, posk, mask, Bm);
    hipLaunchKernelGGL(k_attn, dim3(1024), dim3(256), 0, stream,
                       Qh, Kh, Vth, Bm, aoutb);
    hipLaunchKernelGGL(k_oproj, dim3(128), dim3(256), 0, stream,
                       aoutb, wWt + (3 << 16), bo, out);
}

// Round 4
// 530.329 us; speedup vs baseline: 1.4913x; 1.0055x over previous
//
#include <hip/hip_runtime.h>
#include <hip/hip_bf16.h>

#define TT 1024
#define FF 256

typedef float  f4v  __attribute__((ext_vector_type(4)));
typedef float  f16v __attribute__((ext_vector_type(16)));
typedef __bf16 bf8v __attribute__((ext_vector_type(8)));
typedef unsigned short us8v __attribute__((ext_vector_type(8)));
typedef unsigned short us4v __attribute__((ext_vector_type(4)));

static __device__ __forceinline__ unsigned short f2bf(float x) {
    return __builtin_bit_cast(unsigned short, (__bf16)x);
}
static __device__ __forceinline__ float bf2f(unsigned short u) {
    return (float)__builtin_bit_cast(__bf16, u);
}
static __device__ __forceinline__ bf8v us2bf(us8v v) {
    return __builtin_bit_cast(bf8v, v);
}

// ---------------------------------------------------------------------------
// K0: weight prep — W[k][n] fp32 -> Wt[n][k] bf16, 4 matrices (Q,K,V,O).
// ---------------------------------------------------------------------------
__global__ __launch_bounds__(256) void k_wprep(
    const float* __restrict__ Wq, const float* __restrict__ Wk,
    const float* __restrict__ Wv, const float* __restrict__ Wo,
    unsigned short* __restrict__ Wt)
{
    __shared__ unsigned short T[32][36];
    const float* W = (blockIdx.y == 0) ? Wq : (blockIdx.y == 1) ? Wk
                   : (blockIdx.y == 2) ? Wv : Wo;
    unsigned short* dst = Wt + (blockIdx.y << 16);
    const int kt = (blockIdx.x >> 3) << 5, nt = (blockIdx.x & 7) << 5;
    const int r = threadIdx.x >> 3, c0 = (threadIdx.x & 7) << 2;
    const f4v w = *(const f4v*)&W[(kt + r) * FF + nt + c0];
    #pragma unroll
    for (int j = 0; j < 4; ++j) T[c0 + j][r] = f2bf(w[j]);
    __syncthreads();
    *(us4v*)&dst[(nt + r) * FF + kt + c0] = *(const us4v*)&T[r][c0];
}

// ---------------------------------------------------------------------------
// K1: LayerNorm(x) -> xn_bf16 ; cast q_in -> bf16.
// ---------------------------------------------------------------------------
__global__ __launch_bounds__(256) void k_ln(
    const float* __restrict__ x, const float* __restrict__ qin,
    const float* __restrict__ lng, const float* __restrict__ lnb,
    unsigned short* __restrict__ xn_bf, unsigned short* __restrict__ qin_bf)
{
    const int tid = threadIdx.x, lane = tid & 63, wv = tid >> 6;
    const int r0 = blockIdx.x << 4;

    #pragma unroll
    for (int u = 0; u < 4; ++u) {
        const int i4 = ((u << 8) + tid) << 2;
        const int r = i4 >> 8, c = i4 & 255;
        const f4v qv = *(const f4v*)&qin[(r0 + r) * FF + c];
        us4v o;
        #pragma unroll
        for (int j = 0; j < 4; ++j) o[j] = f2bf(qv[j]);
        *(us4v*)&qin_bf[(r0 + r) * FF + c] = o;
    }

    #pragma unroll
    for (int rr = 0; rr < 4; ++rr) {
        const int row = r0 + (wv << 2) + rr;
        float v[4], s = 0.f, s2 = 0.f;
        #pragma unroll
        for (int c4 = 0; c4 < 4; ++c4) {
            v[c4] = x[row * FF + (c4 << 6) + lane];
            s += v[c4]; s2 += v[c4] * v[c4];
        }
        #pragma unroll
        for (int off = 1; off < 64; off <<= 1) {
            s  += __shfl_xor(s, off);
            s2 += __shfl_xor(s2, off);
        }
        const float mu  = s * (1.f / FF);
        const float rsd = rsqrtf(s2 * (1.f / FF) - mu * mu + 1e-5f);
        #pragma unroll
        for (int c4 = 0; c4 < 4; ++c4) {
            const int c = (c4 << 6) + lane;
            xn_bf[row * FF + c] = f2bf((v[c4] - mu) * rsd * lng[c] + lnb[c]);
        }
    }
}

// ---------------------------------------------------------------------------
// K2: MFMA projections.  z=0: Qh = (qin@Wq + bq)*0.125; z=1: Kh = xn@Wk + bk;
// z=2: Vt = (xn@Wv + bv)^T stored [bh][d][t].
// ---------------------------------------------------------------------------
__global__ __launch_bounds__(256) void k_proj(
    const unsigned short* __restrict__ qin_bf, const unsigned short* __restrict__ xn_bf,
    const unsigned short* __restrict__ Wt,
    const float* __restrict__ bq, const float* __restrict__ bk, const float* __restrict__ bv,
    unsigned short* __restrict__ Qh, unsigned short* __restrict__ Kh,
    unsigned short* __restrict__ Vt)
{
    __shared__ __align__(16) unsigned short As[64 * 264];
    const int z = blockIdx.y;
    const unsigned short* A = (z == 0) ? qin_bf : xn_bf;
    const unsigned short* W = Wt + (z << 16);
    const float* bias = (z == 0) ? bq : (z == 1) ? bk : bv;
    unsigned short* dst = (z == 0) ? Qh : (z == 1) ? Kh : Vt;
    const int tid = threadIdx.x;
    const int m0 = blockIdx.x << 6;

    #pragma unroll
    for (int u = 0; u < 8; ++u) {
        const int idx = (u << 8) + tid;
        const int r = idx >> 5, c = (idx & 31) << 3;
        *(us8v*)&As[r * 264 + c] = *(const us8v*)&A[(m0 + r) * FF + c];
    }
    __syncthreads();

    const int lane = tid & 63, nw = tid >> 6, gq = lane >> 5, l31 = lane & 31;
    f16v acc[2][2];
    #pragma unroll
    for (int i = 0; i < 2; ++i)
        #pragma unroll
        for (int j = 0; j < 2; ++j)
            #pragma unroll
            for (int e = 0; e < 16; ++e) acc[i][j][e] = 0.f;

    for (int ks = 0; ks < 16; ++ks) {
        const int k0 = (ks << 4) + (gq << 3);
        bf8v af[2], wf[2];
        af[0] = us2bf(*(const us8v*)&As[l31 * 264 + k0]);
        af[1] = us2bf(*(const us8v*)&As[(32 + l31) * 264 + k0]);
        wf[0] = us2bf(*(const us8v*)&W[((nw << 6) + l31) * FF + k0]);
        wf[1] = us2bf(*(const us8v*)&W[((nw << 6) + 32 + l31) * FF + k0]);
        if (z == 2) {
            #pragma unroll
            for (int ti = 0; ti < 2; ++ti)
                #pragma unroll
                for (int tj = 0; tj < 2; ++tj)
                    acc[ti][tj] = __builtin_amdgcn_mfma_f32_32x32x16_bf16(
                        wf[tj], af[ti], acc[ti][tj], 0, 0, 0);
        } else {
            #pragma unroll
            for (int ti = 0; ti < 2; ++ti)
                #pragma unroll
                for (int tj = 0; tj < 2; ++tj)
                    acc[ti][tj] = __builtin_amdgcn_mfma_f32_32x32x16_bf16(
                        af[ti], wf[tj], acc[ti][tj], 0, 0, 0);
        }
    }

    if (z != 2) {
        #pragma unroll
        for (int ti = 0; ti < 2; ++ti)
            #pragma unroll
            for (int tj = 0; tj < 2; ++tj)
                #pragma unroll
                for (int reg = 0; reg < 16; ++reg) {
                    const int row = (reg & 3) + ((reg >> 2) << 3) + (gq << 2);
                    const int tg = m0 + (ti << 5) + row;
                    const int n = (nw << 6) + (tj << 5) + l31;
                    float val = acc[ti][tj][reg] + bias[n];
                    if (z == 0) val *= 0.125f;
                    const int b = tg >> 10, t = tg & 1023;
                    dst[(((b << 2) + nw) << 16) + (t << 6) + (tj << 5) + l31] = f2bf(val);
                }
    } else {
        #pragma unroll
        for (int ti = 0; ti < 2; ++ti)
            #pragma unroll
            for (int tj = 0; tj < 2; ++tj)
                #pragma unroll
                for (int reg = 0; reg < 16; ++reg) {
                    const int row = (reg & 3) + ((reg >> 2) << 3) + (gq << 2);
                    const int d = (tj << 5) + row;
                    const int tg = m0 + (ti << 5) + l31;
                    const float val = acc[ti][tj][reg] + bias[(nw << 6) + d];
                    const int b = tg >> 10, t = tg & 1023;
                    dst[(((b << 2) + nw) << 16) + (d << 10) + t] = f2bf(val);
                }
    }
}

// ---------------------------------------------------------------------------
// K3: relative-position term with mask+scale folded (UNCHANGED from R3).
// Bm[bh][q][t] = mask ? Qh_scaled[bh][q].posk[q][t] : -3e38  (bf16)
// ---------------------------------------------------------------------------
__global__ __launch_bounds__(256) void k_bterm(
    const unsigned short* __restrict__ Qh, const float* __restrict__ posk,
    const int* __restrict__ mask, unsigned short* __restrict__ Bm)
{
    const int tid = threadIdx.x, lane = tid & 63, wv = tid >> 6;
    const int gq = lane >> 5, m = lane & 31;
    const int q = blockIdx.y;
    const int t = (blockIdx.x << 7) + (wv << 5) + m;

    bf8v afr[4];
    #pragma unroll
    for (int kk = 0; kk < 4; ++kk)
        afr[kk] = us2bf(*(const us8v*)&Qh[(m << 16) + (q << 6) + (kk << 4) + (gq << 3)]);

    bf8v bfr[4];
    #pragma unroll
    for (int kk = 0; kk < 4; ++kk) {
        const int d0 = (kk << 4) + (gq << 3);
        const f4v p0 = *(const f4v*)&posk[(((q << 10) + t) << 6) + d0];
        const f4v p1 = *(const f4v*)&posk[(((q << 10) + t) << 6) + d0 + 4];
        bf8v bb;
        bb[0] = (__bf16)p0[0]; bb[1] = (__bf16)p0[1];
        bb[2] = (__bf16)p0[2]; bb[3] = (__bf16)p0[3];
        bb[4] = (__bf16)p1[0]; bb[5] = (__bf16)p1[1];
        bb[6] = (__bf16)p1[2]; bb[7] = (__bf16)p1[3];
        bfr[kk] = bb;
    }

    f16v acc;
    #pragma unroll
    for (int i = 0; i < 16; ++i) acc[i] = 0.f;
    #pragma unroll
    for (int kk = 0; kk < 4; ++kk)
        acc = __builtin_amdgcn_mfma_f32_32x32x16_bf16(afr[kk], bfr[kk], acc, 0, 0, 0);

    int mk[4];
    #pragma unroll
    for (int g = 0; g < 4; ++g)   // b = 2g + gq for reg group g
        mk[g] = mask[(((g << 1) + gq) << 20) + (q << 10) + t];
    #pragma unroll
    for (int reg = 0; reg < 16; ++reg) {
        const int g = reg >> 2;
        const int bhr = (reg & 3) + (g << 3) + (gq << 2);
        const float val = mk[g] ? acc[reg] : -3.0e38f;
        Bm[(bhr << 20) + (q << 10) + t] = f2bf(val);
    }
}

// ---------------------------------------------------------------------------
// K4 (REWRITTEN): transposed flash attention.  S^T = K.Q^T so q = lane&15 is
// a per-lane column: softmax max/sum = in-register reduce + 2 shuffles.
// PV: O^T[d][q] = V^T.P^T, A direct from Vt[bh][d][t], B from wave-private
// PsT LDS (intra-wave, no barrier).  4 waves = (2 q-groups x 2 t-halves);
// one __syncthreads() total (t-half merge).  Grid 1024 = 32 bh x 32 q-tiles.
// ---------------------------------------------------------------------------
__global__ __launch_bounds__(256, 4) void k_attn(
    const unsigned short* __restrict__ Qh, const unsigned short* __restrict__ Kh,
    const unsigned short* __restrict__ Vt, const unsigned short* __restrict__ Bm,
    unsigned short* __restrict__ aout_bf)
{
    __shared__ __align__(16) unsigned short PsT[4][16 * 132]; // per-wave [q][t]
    __shared__ __align__(16) float OLDS[2][16 * 68];          // [qg][q][d]
    __shared__ float MLDS[2][2][16];                          // [qg][{m,l}][q]

    const int tid = threadIdx.x, lane = tid & 63, wv = tid >> 6;
    const int l15 = lane & 15, quad = lane >> 4;
    const int qg = wv & 1, th = wv >> 1;
    const int blk = blockIdx.x;
    const int bh = ((blk & 7) << 2) | ((blk >> 3) & 3);  // XCD swizzle
    const int qt = blk >> 5;
    const int b = bh >> 2, h = bh & 3;
    const int q0w = (qt << 5) + (qg << 4);               // wave's 16 q rows

    // Q B-fragments (B[k=d][n=q], n = l15): loaded once, straight from global
    bf8v qb0, qb1;
    {
        const int base = (bh << 16) + ((q0w + l15) << 6) + (quad << 3);
        qb0 = us2bf(*(const us8v*)&Qh[base]);
        qb1 = us2bf(*(const us8v*)&Qh[base + 32]);
    }

    f4v O[4];
    #pragma unroll
    for (int i = 0; i < 4; ++i) { O[i][0]=0.f; O[i][1]=0.f; O[i][2]=0.f; O[i][3]=0.f; }
    float m_run = -3.0e38f, l_run = 0.f;

    for (int cc = 0; cc < 4; ++cc) {
        const int t0c = (th << 9) + (cc << 7);   // this wave's 128-t chunk

        // ---- S^T = K Q^T : A[m=t][k=d] from Kh rows, 16 MFMA ----
        f4v s[8];
        #pragma unroll
        for (int nf = 0; nf < 8; ++nf) {
            const int krow = (bh << 16) + ((t0c + (nf << 4) + l15) << 6) + (quad << 3);
            const bf8v ka0 = us2bf(*(const us8v*)&Kh[krow]);
            const bf8v ka1 = us2bf(*(const us8v*)&Kh[krow + 32]);
            f4v z;
            z[0]=0.f; z[1]=0.f; z[2]=0.f; z[3]=0.f;
            z = __builtin_amdgcn_mfma_f32_16x16x32_bf16(ka0, qb0, z, 0, 0, 0);
            z = __builtin_amdgcn_mfma_f32_16x16x32_bf16(ka1, qb1, z, 0, 0, 0);
            s[nf] = z;
        }

        // ---- add Bm (mask & 1/sqrt(dk) pre-folded): rows t=quad*4+r+nf*16 ----
        #pragma unroll
        for (int nf = 0; nf < 8; ++nf) {
            const us4v bm = *(const us4v*)&Bm[(bh << 20) + ((q0w + l15) << 10)
                                             + t0c + (nf << 4) + (quad << 2)];
            #pragma unroll
            for (int r = 0; r < 4; ++r) s[nf][r] += bf2f(bm[r]);
        }

        // ---- chunk max for column q = l15: in-register + 2 shuffles ----
        f4v mx = s[0];
        #pragma unroll
        for (int nf = 1; nf < 8; ++nf) {
            mx[0] = fmaxf(mx[0], s[nf][0]); mx[1] = fmaxf(mx[1], s[nf][1]);
            mx[2] = fmaxf(mx[2], s[nf][2]); mx[3] = fmaxf(mx[3], s[nf][3]);
        }
        float cm = fmaxf(fmaxf(mx[0], mx[1]), fmaxf(mx[2], mx[3]));
        cm = fmaxf(cm, __shfl_xor(cm, 16));
        cm = fmaxf(cm, __shfl_xor(cm, 32));

        const float mn = fmaxf(m_run, cm);
        const float alpha = __expf(m_run - mn);
        m_run = mn;
        l_run *= alpha;
        #pragma unroll
        for (int i = 0; i < 4; ++i) {
            O[i][0] *= alpha; O[i][1] *= alpha; O[i][2] *= alpha; O[i][3] *= alpha;
        }

        // ---- exp, write P^T to wave-private LDS [q][t], row-sum ----
        float rs = 0.f;
        #pragma unroll
        for (int nf = 0; nf < 8; ++nf) {
            const float p0 = __expf(s[nf][0] - mn);
            const float p1 = __expf(s[nf][1] - mn);
            const float p2 = __expf(s[nf][2] - mn);
            const float p3 = __expf(s[nf][3] - mn);
            const int ea = l15 * 132 + (nf << 4) + (quad << 2);
            *(unsigned int*)&PsT[wv][ea] =
                (unsigned int)f2bf(p0) | ((unsigned int)f2bf(p1) << 16);
            *(unsigned int*)&PsT[wv][ea + 2] =
                (unsigned int)f2bf(p2) | ((unsigned int)f2bf(p3) << 16);
            rs += (p0 + p1) + (p2 + p3);
        }
        rs += __shfl_xor(rs, 16);
        rs += __shfl_xor(rs, 32);
        l_run += rs;

        // ---- PV: O^T[d][q] += V^T P^T, A from Vt global, B from PsT ----
        #pragma unroll
        for (int tc = 0; tc < 4; ++tc) {
            const int eb = l15 * 132 + (tc << 5) + (quad << 3);
            const us4v plo = *(const us4v*)&PsT[wv][eb];
            const us4v phi = *(const us4v*)&PsT[wv][eb + 4];
            us8v pc;
            pc[0]=plo[0]; pc[1]=plo[1]; pc[2]=plo[2]; pc[3]=plo[3];
            pc[4]=phi[0]; pc[5]=phi[1]; pc[6]=phi[2]; pc[7]=phi[3];
            const bf8v pb = us2bf(pc);
            #pragma unroll
            for (int dt = 0; dt < 4; ++dt) {
                const bf8v va = us2bf(*(const us8v*)&Vt[(bh << 16)
                    + (((dt << 4) + l15) << 10) + t0c + (tc << 5) + (quad << 3)]);
                O[dt] = __builtin_amdgcn_mfma_f32_16x16x32_bf16(va, pb, O[dt], 0, 0, 0);
            }
        }
    }

    // ---- merge the two t-halves (one barrier) ----
    if (th == 1) {
        #pragma unroll
        for (int dt = 0; dt < 4; ++dt)
            *(f4v*)&OLDS[qg][l15 * 68 + (dt << 4) + (quad << 2)] = O[dt];
        if (quad == 0) { MLDS[qg][0][l15] = m_run; MLDS[qg][1][l15] = l_run; }
    }
    __syncthreads();
    if (th == 0) {
        const float m1 = MLDS[qg][0][l15];
        const float l1 = MLDS[qg][1][l15];
        const float mm = fmaxf(m_run, m1);
        const float a0 = __expf(m_run - mm);
        const float a1 = __expf(m1 - mm);
        const float linv = 1.f / (l_run * a0 + l1 * a1);
        const int orow = ((b << 10) + q0w + l15) * FF + (h << 6);
        #pragma unroll
        for (int dt = 0; dt < 4; ++dt) {
            const f4v o1 = *(const f4v*)&OLDS[qg][l15 * 68 + (dt << 4) + (quad << 2)];
            us4v ov;
            #pragma unroll
            for (int r = 0; r < 4; ++r)
                ov[r] = f2bf((O[dt][r] * a0 + o1[r] * a1) * linv);
            *(us4v*)&aout_bf[orow + (dt << 4) + (quad << 2)] = ov;
        }
    }
}

// ---------------------------------------------------------------------------
// K5: out = aout @ Wo + bo  (MFMA, fp32 output)
// ---------------------------------------------------------------------------
__global__ __launch_bounds__(256) void k_oproj(
    const unsigned short* __restrict__ aout_bf, const unsigned short* __restrict__ Wot,
    const float* __restrict__ bo, float* __restrict__ out)
{
    __shared__ __align__(16) unsigned short As[64 * 264];
    const int tid = threadIdx.x;
    const int m0 = blockIdx.x << 6;

    #pragma unroll
    for (int u = 0; u < 8; ++u) {
        const int idx = (u << 8) + tid;
        const int r = idx >> 5, c = (idx & 31) << 3;
        *(us8v*)&As[r * 264 + c] = *(const us8v*)&aout_bf[(m0 + r) * FF + c];
    }
    __syncthreads();

    const int lane = tid & 63, nw = tid >> 6, gq = lane >> 5, l31 = lane & 31;
    f16v acc[2][2];
    #pragma unroll
    for (int i = 0; i < 2; ++i)
        #pragma unroll
        for (int j = 0; j < 2; ++j)
            #pragma unroll
            for (int e = 0; e < 16; ++e) acc[i][j][e] = 0.f;

    for (int ks = 0; ks < 16; ++ks) {
        const int k0 = (ks << 4) + (gq << 3);
        bf8v af[2], wf[2];
        af[0] = us2bf(*(const us8v*)&As[l31 * 264 + k0]);
        af[1] = us2bf(*(const us8v*)&As[(32 + l31) * 264 + k0]);
        wf[0] = us2bf(*(const us8v*)&Wot[((nw << 6) + l31) * FF + k0]);
        wf[1] = us2bf(*(const us8v*)&Wot[((nw << 6) + 32 + l31) * FF + k0]);
        #pragma unroll
        for (int ti = 0; ti < 2; ++ti)
            #pragma unroll
            for (int tj = 0; tj < 2; ++tj)
                acc[ti][tj] = __builtin_amdgcn_mfma_f32_32x32x16_bf16(
                    af[ti], wf[tj], acc[ti][tj], 0, 0, 0);
    }

    #pragma unroll
    for (int ti = 0; ti < 2; ++ti)
        #pragma unroll
        for (int tj = 0; tj < 2; ++tj)
            #pragma unroll
            for (int reg = 0; reg < 16; ++reg) {
                const int row = (reg & 3) + ((reg >> 2) << 3) + (gq << 2);
                const int tg = m0 + (ti << 5) + row;
                const int n = (nw << 6) + (tj << 5) + l31;
                out[tg * FF + n] = acc[ti][tj][reg] + bo[n];
            }
}

// ---------------------------------------------------------------------------
// ws layout (MB): Wt 0..0.5 | qin_bf @1 | xn_bf @5 | Qh @9 | Kh @13 |
// Vt @17 | aout_bf @21 | Bm (full 32x1024x1024 bf16 = 64MB) @25..89.
// ---------------------------------------------------------------------------
extern "C" void kernel_launch(void* const* d_in, const int* in_sizes, int n_in,
                              void* d_out, int out_size, void* d_ws, size_t ws_size,
                              hipStream_t stream)
{
    const float* x    = (const float*)d_in[0];
    const float* qin  = (const float*)d_in[1];
    const float* posk = (const float*)d_in[2];
    const int*   mask = (const int*)d_in[3];
    const float* ln_g = (const float*)d_in[4];
    const float* ln_b = (const float*)d_in[5];
    const float* Wq   = (const float*)d_in[6];
    const float* bq   = (const float*)d_in[7];
    const float* Wk   = (const float*)d_in[8];
    const float* bk   = (const float*)d_in[9];
    const float* Wv   = (const float*)d_in[10];
    const float* bv   = (const float*)d_in[11];
    const float* Wo   = (const float*)d_in[12];
    const float* bo   = (const float*)d_in[13];
    float* out = (float*)d_out;

    char* ws = (char*)d_ws;
    unsigned short* wWt   = (unsigned short*)(ws);
    unsigned short* qinb  = (unsigned short*)(ws + (size_t)(1u << 20));
    unsigned short* xnb   = (unsigned short*)(ws + (size_t)(5u << 20));
    unsigned short* Qh    = (unsigned short*)(ws + (size_t)(9u << 20));
    unsigned short* Kh    = (unsigned short*)(ws + (size_t)(13u << 20));
    unsigned short* Vth   = (unsigned short*)(ws + (size_t)(17u << 20));
    unsigned short* aoutb = (unsigned short*)(ws + (size_t)(21u << 20));
    unsigned short* Bm    = (unsigned short*)(ws + (size_t)(25u << 20));

    hipLaunchKernelGGL(k_wprep, dim3(64, 4), dim3(256), 0, stream, Wq, Wk, Wv, Wo, wWt);
    hipLaunchKernelGGL(k_ln, dim3(512), dim3(256), 0, stream,
                       x, qin, ln_g, ln_b, xnb, qinb);
    hipLaunchKernelGGL(k_proj, dim3(128, 3), dim3(256), 0, stream,
                       qinb, xnb, wWt, bq, bk, bv, Qh, Kh, Vth);
    hipLaunchKernelGGL(k_bterm, dim3(8, 1024), dim3(256), 0, stream,
                       Qh, posk, mask, Bm);
    hipLaunchKernelGGL(k_attn, dim3(1024), dim3(256), 0, stream,
                       Qh, Kh, Vth, Bm, aoutb);
    hipLaunchKernelGGL(k_oproj, dim3(128), dim3(256), 0, stream,
                       aoutb, wWt + (3 << 16), bo, out);
}